// Round 1
// baseline (1738.884 us; speedup 1.0000x reference)
//
#include <hip/hip_runtime.h>
#include <hip/hip_bf16.h>

#define NN 500000
#define NE 1250000
#define NF 128
#define NH 64
#define NC 10
#define NG 512

typedef __attribute__((ext_vector_type(8))) short short8;
typedef __attribute__((ext_vector_type(4))) float floatx4;

__device__ __forceinline__ unsigned short f2bf(float f) {
  unsigned u = __builtin_bit_cast(unsigned, f);
  u += 0x7FFFu + ((u >> 16) & 1u);
  return (unsigned short)(u >> 16);
}

__global__ __launch_bounds__(256) void k_zero(int* __restrict__ p, int n) {
  int i = blockIdx.x * 256 + threadIdx.x;
  if (i < n) p[i] = 0;
}

__global__ __launch_bounds__(256) void k_deg(const int* __restrict__ dst, int* __restrict__ deg) {
  int e = blockIdx.x * 256 + threadIdx.x;
  if (e < NE) atomicAdd(&deg[dst[e]], 1);
}

__global__ __launch_bounds__(256) void k_dinv(const int* __restrict__ deg, float* __restrict__ dinv) {
  int i = blockIdx.x * 256 + threadIdx.x;
  if (i < NN) dinv[i] = rsqrtf((float)(deg[i] + 1));
}

// W [K,64] row-major f32 -> Wt [64,K] bf16 (transposed for MFMA B-frag b128 loads)
__global__ __launch_bounds__(256) void k_prepw(const float* __restrict__ W,
                                               unsigned short* __restrict__ Wt, int K) {
  int idx = blockIdx.x * 256 + threadIdx.x;
  if (idx < K * 64) {
    int k = idx / 64, n = idx % 64;
    Wt[n * K + k] = f2bf(W[idx]);
  }
}

// GEMM: out_lin[M,64] = act(Ain[M,K]) @ W[K,64];  agg initialized with self-loop term lin*dinv^2.
// PRE=true applies relu(a + bias) to the input on load (bias/relu of previous layer fused here).
// mfma_f32_16x16x32_bf16: A[m=lane&15][k=quad*8+j], B[n=lane&15][k=quad*8+j], D row=quad*4+i col=lane&15.
template<int K, bool PRE>
__global__ __launch_bounds__(256) void k_gemm(const float* __restrict__ Ain,
                                              const float* __restrict__ bias,
                                              const unsigned short* __restrict__ Wt,
                                              const float* __restrict__ dinv,
                                              float* __restrict__ lin,
                                              float* __restrict__ agg) {
  constexpr int KC = K / 32;
  constexpr int SP = K + 8;  // pad 8 shorts (16B): word-stride 4 mod 32 -> conflict-free-ish frag reads
  __shared__ unsigned short Wl[64 * SP];
  int tid = threadIdx.x;
  for (int idx = tid * 8; idx < 64 * K; idx += 2048) {
    int n = idx / K, k = idx % K;
    *(short8*)&Wl[n * SP + k] = *(const short8*)&Wt[idx];
  }
  __syncthreads();

  int lane = tid & 63, wave = tid >> 6;
  int quad = lane >> 4, l16 = lane & 15;

  short8 bfrag[4][KC];
#pragma unroll
  for (int nt = 0; nt < 4; ++nt)
#pragma unroll
    for (int kc = 0; kc < KC; ++kc)
      bfrag[nt][kc] = *(const short8*)&Wl[(nt * 16 + l16) * SP + kc * 32 + quad * 8];

  floatx4 bb0[KC], bb1[KC];
  if (PRE) {
#pragma unroll
    for (int kc = 0; kc < KC; ++kc) {
      bb0[kc] = *(const floatx4*)&bias[kc * 32 + quad * 8];
      bb1[kc] = *(const floatx4*)&bias[kc * 32 + quad * 8 + 4];
    }
  }

  const int ntiles = NN / 16;  // 31250, exact
  for (int t = blockIdx.x * 4 + wave; t < ntiles; t += gridDim.x * 4) {
    int rowbase = t * 16;
    int arow = rowbase + l16;
    floatx4 z = {0.f, 0.f, 0.f, 0.f};
    floatx4 acc[4] = {z, z, z, z};
#pragma unroll
    for (int kc = 0; kc < KC; ++kc) {
      const float* Af = Ain + (size_t)arow * K + kc * 32 + quad * 8;
      floatx4 a0 = *(const floatx4*)Af;
      floatx4 a1 = *(const floatx4*)(Af + 4);
      if (PRE) {
        a0.x = fmaxf(a0.x + bb0[kc].x, 0.f); a0.y = fmaxf(a0.y + bb0[kc].y, 0.f);
        a0.z = fmaxf(a0.z + bb0[kc].z, 0.f); a0.w = fmaxf(a0.w + bb0[kc].w, 0.f);
        a1.x = fmaxf(a1.x + bb1[kc].x, 0.f); a1.y = fmaxf(a1.y + bb1[kc].y, 0.f);
        a1.z = fmaxf(a1.z + bb1[kc].z, 0.f); a1.w = fmaxf(a1.w + bb1[kc].w, 0.f);
      }
      short8 af;
      af[0] = (short)f2bf(a0.x); af[1] = (short)f2bf(a0.y);
      af[2] = (short)f2bf(a0.z); af[3] = (short)f2bf(a0.w);
      af[4] = (short)f2bf(a1.x); af[5] = (short)f2bf(a1.y);
      af[6] = (short)f2bf(a1.z); af[7] = (short)f2bf(a1.w);
#pragma unroll
      for (int nt = 0; nt < 4; ++nt)
        acc[nt] = __builtin_amdgcn_mfma_f32_16x16x32_bf16(af, bfrag[nt][kc], acc[nt], 0, 0, 0);
    }
#pragma unroll
    for (int i = 0; i < 4; ++i) {
      int r = rowbase + quad * 4 + i;
      float dv = dinv[r];
      float dv2 = dv * dv;
      float* lp = lin + (size_t)r * 64 + l16;
      float* ap = agg + (size_t)r * 64 + l16;
#pragma unroll
      for (int nt = 0; nt < 4; ++nt) {
        float v = acc[nt][i];
        lp[nt * 16] = v;
        ap[nt * 16] = v * dv2;
      }
    }
  }
}

// wave-per-edge scatter: lane = feature. agg[dst] += lin[src] * dinv[src]*dinv[dst]
__global__ __launch_bounds__(256) void k_scatter(const float* __restrict__ lin,
                                                 const int* __restrict__ ei,
                                                 const float* __restrict__ dinv,
                                                 float* __restrict__ agg) {
  int e = blockIdx.x * 4 + (threadIdx.x >> 6);
  if (e >= NE) return;
  int lane = threadIdx.x & 63;
  int s = ei[e];
  int d = ei[NE + e];
  float nrm = dinv[s] * dinv[d];
  float v = lin[(size_t)s * 64 + lane] * nrm;
  atomicAdd(&agg[(size_t)d * 64 + lane], v);
}

// one block per graph; batch sorted -> binary search boundaries; fused bias+relu of layer 3
__global__ __launch_bounds__(256) void k_pool(const float* __restrict__ agg,
                                              const float* __restrict__ b,
                                              const int* __restrict__ batch,
                                              float* __restrict__ pooled) {
  int g = blockIdx.x;
  int tid = threadIdx.x;
  int c = tid & 63, sub = tid >> 6;

  int lo = 0, hi = NN;
  while (lo < hi) { int mid = (lo + hi) >> 1; if (batch[mid] < g) lo = mid + 1; else hi = mid; }
  int start = lo;
  lo = 0; hi = NN;
  while (lo < hi) { int mid = (lo + hi) >> 1; if (batch[mid] < g + 1) lo = mid + 1; else hi = mid; }
  int end = lo;

  float bc = b[c];
  float s = 0.f, m = -1e30f;
  for (int i = start + sub; i < end; i += 4) {
    float v = fmaxf(agg[(size_t)i * 64 + c] + bc, 0.f);
    s += v;
    m = fmaxf(m, v);
  }
  __shared__ float ss[256], sm[256];
  ss[tid] = s; sm[tid] = m;
  __syncthreads();
  if (sub == 0) {
#pragma unroll
    for (int j = 1; j < 4; ++j) { s += ss[j * 64 + c]; m = fmaxf(m, sm[j * 64 + c]); }
    int cnt = end - start;
    float mean = cnt > 0 ? s / (float)cnt : 0.f;
    if (cnt == 0) m = 0.f;
    pooled[g * 128 + c] = mean;
    pooled[g * 128 + 64 + c] = m;
  }
}

__global__ __launch_bounds__(128) void k_head(const float* __restrict__ pooled,
                                              const float* __restrict__ Wout,
                                              const float* __restrict__ bout,
                                              float* __restrict__ out) {
  __shared__ float p[128];
  int g = blockIdx.x, tid = threadIdx.x;
  p[tid] = pooled[g * 128 + tid];
  __syncthreads();
  if (tid < NC) {
    float acc = bout[tid];
#pragma unroll 8
    for (int c = 0; c < 128; ++c) acc += p[c] * Wout[c * NC + tid];
    out[g * NC + tid] = acc;
  }
}

extern "C" void kernel_launch(void* const* d_in, const int* in_sizes, int n_in,
                              void* d_out, int out_size, void* d_ws, size_t ws_size,
                              hipStream_t stream) {
  const float* x     = (const float*)d_in[0];
  const int*   ei    = (const int*)d_in[1];
  const int*   batch = (const int*)d_in[2];
  const float* W0    = (const float*)d_in[3];
  const float* b0    = (const float*)d_in[4];
  const float* W1    = (const float*)d_in[5];
  const float* b1    = (const float*)d_in[6];
  const float* W2    = (const float*)d_in[7];
  const float* b2    = (const float*)d_in[8];
  const float* Wout  = (const float*)d_in[9];
  const float* bout  = (const float*)d_in[10];
  float* out = (float*)d_out;

  char* ws = (char*)d_ws;
  size_t off = 0;
  auto alloc = [&](size_t bytes) -> void* {
    void* p = ws + off;
    off = (off + bytes + 255) & ~(size_t)255;
    return p;
  };
  int*   deg  = (int*)alloc((size_t)NN * 4);
  float* dinv = (float*)alloc((size_t)NN * 4);
  float* A    = (float*)alloc((size_t)NN * 64 * 4);  // lin output of each GEMM
  float* C    = (float*)alloc((size_t)NN * 64 * 4);  // agg buffer (layers 1,3)
  float* D    = (float*)alloc((size_t)NN * 64 * 4);  // agg buffer (layer 2)
  unsigned short* Wt0 = (unsigned short*)alloc(64 * 128 * 2);
  unsigned short* Wt1 = (unsigned short*)alloc(64 * 64 * 2);
  unsigned short* Wt2 = (unsigned short*)alloc(64 * 64 * 2);
  float* pooled = (float*)alloc((size_t)NG * 128 * 4);

  k_zero<<<(NN + 255) / 256, 256, 0, stream>>>(deg, NN);
  k_deg<<<(NE + 255) / 256, 256, 0, stream>>>(ei + NE, deg);
  k_dinv<<<(NN + 255) / 256, 256, 0, stream>>>(deg, dinv);
  k_prepw<<<(128 * 64 + 255) / 256, 256, 0, stream>>>(W0, Wt0, 128);
  k_prepw<<<(64 * 64 + 255) / 256, 256, 0, stream>>>(W1, Wt1, 64);
  k_prepw<<<(64 * 64 + 255) / 256, 256, 0, stream>>>(W2, Wt2, 64);

  // layer 1: x (raw f32) -> lin A, agg C (self-loop init)
  k_gemm<128, false><<<2048, 256, 0, stream>>>(x, nullptr, Wt0, dinv, A, C);
  k_scatter<<<NE / 4, 256, 0, stream>>>(A, ei, dinv, C);
  // layer 2: reads C with fused relu(.+b0) -> lin A, agg D
  k_gemm<64, true><<<2048, 256, 0, stream>>>(C, b0, Wt1, dinv, A, D);
  k_scatter<<<NE / 4, 256, 0, stream>>>(A, ei, dinv, D);
  // layer 3: reads D with fused relu(.+b1) -> lin A, agg C
  k_gemm<64, true><<<2048, 256, 0, stream>>>(D, b1, Wt2, dinv, A, C);
  k_scatter<<<NE / 4, 256, 0, stream>>>(A, ei, dinv, C);
  // pool (fused relu(.+b2)) + head
  k_pool<<<NG, 256, 0, stream>>>(C, b2, batch, pooled);
  k_head<<<NG, 128, 0, stream>>>(pooled, Wout, bout, out);
}

// Round 2
// 1353.069 us; speedup vs baseline: 1.2851x; 1.2851x over previous
//
#include <hip/hip_runtime.h>
#include <hip/hip_bf16.h>

#define NN 500000
#define NE 1250000
#define NF 128
#define NH 64
#define NC 10
#define NG 512

typedef __attribute__((ext_vector_type(8))) short short8;
typedef __attribute__((ext_vector_type(4))) float floatx4;

__device__ __forceinline__ unsigned short f2bf(float f) {
  unsigned u = __builtin_bit_cast(unsigned, f);
  u += 0x7FFFu + ((u >> 16) & 1u);
  return (unsigned short)(u >> 16);
}
__device__ __forceinline__ float bf2f(unsigned short u) {
  return __builtin_bit_cast(float, (unsigned)u << 16);
}

__global__ __launch_bounds__(256) void k_zero(int* __restrict__ p, int n) {
  int i = blockIdx.x * 256 + threadIdx.x;
  if (i < n) p[i] = 0;
}

__global__ __launch_bounds__(256) void k_deg(const int* __restrict__ dst, int* __restrict__ deg) {
  int e = blockIdx.x * 256 + threadIdx.x;
  if (e < NE) atomicAdd(&deg[dst[e]], 1);
}

__global__ __launch_bounds__(256) void k_dinv(const int* __restrict__ deg, float* __restrict__ dinv) {
  int i = blockIdx.x * 256 + threadIdx.x;
  if (i < NN) dinv[i] = rsqrtf((float)(deg[i] + 1));
}

// Assign CSR row starts without a global scan: wave-scan degrees, one atomic per wave.
// Row order in csr[] is arbitrary (only per-row contiguity matters for a sum).
__global__ __launch_bounds__(256) void k_rowstart(const int* __restrict__ deg,
                                                  int* __restrict__ row_start,
                                                  int* __restrict__ cur,
                                                  int* __restrict__ counter) {
  int i = blockIdx.x * 256 + threadIdx.x;
  int lane = threadIdx.x & 63;
  int d = (i < NN) ? deg[i] : 0;
  int incl = d;
#pragma unroll
  for (int off = 1; off < 64; off <<= 1) {
    int n = __shfl_up(incl, off, 64);
    if (lane >= off) incl += n;
  }
  int total = __shfl(incl, 63, 64);
  int base = 0;
  if (lane == 63) base = atomicAdd(counter, total);
  base = __shfl(base, 63, 64);
  if (i < NN) {
    int rs = base + incl - d;
    row_start[i] = rs;
    cur[i] = rs;
  }
}

// Bucket-fill CSR: packed (src, norm) per edge for a single 8B broadcast load in k_agg.
__global__ __launch_bounds__(256) void k_fill(const int* __restrict__ ei,
                                              const float* __restrict__ dinv,
                                              int* __restrict__ cur,
                                              int2* __restrict__ csr) {
  int e = blockIdx.x * 256 + threadIdx.x;
  if (e >= NE) return;
  int s = ei[e];
  int d = ei[NE + e];
  float nrm = dinv[s] * dinv[d];
  int idx = atomicAdd(&cur[d], 1);
  int2 v;
  v.x = s;
  v.y = __builtin_bit_cast(int, nrm);
  csr[idx] = v;
}

// W [K,64] row-major f32 -> Wt [64,K] bf16 (transposed for MFMA B-frag b128 loads)
__global__ __launch_bounds__(256) void k_prepw(const float* __restrict__ W,
                                               unsigned short* __restrict__ Wt, int K) {
  int idx = blockIdx.x * 256 + threadIdx.x;
  if (idx < K * 64) {
    int k = idx / 64, n = idx % 64;
    Wt[n * K + k] = f2bf(W[idx]);
  }
}

// GEMM: linbf[M,64] (bf16) = act(Ain[M,K]) @ W[K,64]
// PRE=true applies relu(a + bias) on load (prev layer's bias/relu fused here).
// mfma_f32_16x16x32_bf16: A[m=l16][k=quad*8+j], B[n=l16][k=quad*8+j], D row=quad*4+i col=l16.
template<int K, bool PRE>
__global__ __launch_bounds__(256) void k_gemm(const float* __restrict__ Ain,
                                              const float* __restrict__ bias,
                                              const unsigned short* __restrict__ Wt,
                                              unsigned short* __restrict__ linbf) {
  constexpr int KC = K / 32;
  constexpr int SP = K + 8;
  __shared__ unsigned short Wl[64 * SP];
  int tid = threadIdx.x;
  for (int idx = tid * 8; idx < 64 * K; idx += 2048) {
    int n = idx / K, k = idx % K;
    *(short8*)&Wl[n * SP + k] = *(const short8*)&Wt[idx];
  }
  __syncthreads();

  int lane = tid & 63, wave = tid >> 6;
  int quad = lane >> 4, l16 = lane & 15;

  short8 bfrag[4][KC];
#pragma unroll
  for (int nt = 0; nt < 4; ++nt)
#pragma unroll
    for (int kc = 0; kc < KC; ++kc)
      bfrag[nt][kc] = *(const short8*)&Wl[(nt * 16 + l16) * SP + kc * 32 + quad * 8];

  floatx4 bb0[KC], bb1[KC];
  if (PRE) {
#pragma unroll
    for (int kc = 0; kc < KC; ++kc) {
      bb0[kc] = *(const floatx4*)&bias[kc * 32 + quad * 8];
      bb1[kc] = *(const floatx4*)&bias[kc * 32 + quad * 8 + 4];
    }
  }

  const int ntiles = NN / 16;  // 31250, exact
  for (int t = blockIdx.x * 4 + wave; t < ntiles; t += gridDim.x * 4) {
    int rowbase = t * 16;
    int arow = rowbase + l16;
    floatx4 z = {0.f, 0.f, 0.f, 0.f};
    floatx4 acc[4] = {z, z, z, z};
#pragma unroll
    for (int kc = 0; kc < KC; ++kc) {
      const float* Af = Ain + (size_t)arow * K + kc * 32 + quad * 8;
      floatx4 a0 = *(const floatx4*)Af;
      floatx4 a1 = *(const floatx4*)(Af + 4);
      if (PRE) {
        a0.x = fmaxf(a0.x + bb0[kc].x, 0.f); a0.y = fmaxf(a0.y + bb0[kc].y, 0.f);
        a0.z = fmaxf(a0.z + bb0[kc].z, 0.f); a0.w = fmaxf(a0.w + bb0[kc].w, 0.f);
        a1.x = fmaxf(a1.x + bb1[kc].x, 0.f); a1.y = fmaxf(a1.y + bb1[kc].y, 0.f);
        a1.z = fmaxf(a1.z + bb1[kc].z, 0.f); a1.w = fmaxf(a1.w + bb1[kc].w, 0.f);
      }
      short8 af;
      af[0] = (short)f2bf(a0.x); af[1] = (short)f2bf(a0.y);
      af[2] = (short)f2bf(a0.z); af[3] = (short)f2bf(a0.w);
      af[4] = (short)f2bf(a1.x); af[5] = (short)f2bf(a1.y);
      af[6] = (short)f2bf(a1.z); af[7] = (short)f2bf(a1.w);
#pragma unroll
      for (int nt = 0; nt < 4; ++nt)
        acc[nt] = __builtin_amdgcn_mfma_f32_16x16x32_bf16(af, bfrag[nt][kc], acc[nt], 0, 0, 0);
    }
#pragma unroll
    for (int i = 0; i < 4; ++i) {
      int r = rowbase + quad * 4 + i;
      unsigned short* lp = linbf + (size_t)r * 64 + l16;
#pragma unroll
      for (int nt = 0; nt < 4; ++nt) lp[nt * 16] = f2bf(acc[nt][i]);
    }
  }
}

// Gather aggregation, wave-per-node, lane=feature:
// agg[r] = lin[r]*dinv[r]^2 + sum_{e: dst=r} lin[src_e]*norm_e   (no atomics)
__global__ __launch_bounds__(256) void k_agg(const unsigned short* __restrict__ linbf,
                                             const float* __restrict__ dinv,
                                             const int* __restrict__ deg,
                                             const int* __restrict__ row_start,
                                             const int2* __restrict__ csr,
                                             float* __restrict__ agg) {
  int r = blockIdx.x * 4 + (threadIdx.x >> 6);
  if (r >= NN) return;
  int c = threadIdx.x & 63;
  float dv = dinv[r];
  float acc = bf2f(linbf[(size_t)r * 64 + c]) * dv * dv;
  int rs = row_start[r];
  int dg = deg[r];
  for (int j = 0; j < dg; ++j) {
    int2 e = csr[rs + j];  // all lanes same address -> broadcast
    float nrm = __builtin_bit_cast(float, e.y);
    acc += nrm * bf2f(linbf[(size_t)e.x * 64 + c]);
  }
  agg[(size_t)r * 64 + c] = acc;
}

// one block per graph; batch sorted -> binary search boundaries; fused bias+relu of layer 3
__global__ __launch_bounds__(256) void k_pool(const float* __restrict__ agg,
                                              const float* __restrict__ b,
                                              const int* __restrict__ batch,
                                              float* __restrict__ pooled) {
  int g = blockIdx.x;
  int tid = threadIdx.x;
  int c = tid & 63, sub = tid >> 6;

  int lo = 0, hi = NN;
  while (lo < hi) { int mid = (lo + hi) >> 1; if (batch[mid] < g) lo = mid + 1; else hi = mid; }
  int start = lo;
  lo = 0; hi = NN;
  while (lo < hi) { int mid = (lo + hi) >> 1; if (batch[mid] < g + 1) lo = mid + 1; else hi = mid; }
  int end = lo;

  float bc = b[c];
  float s = 0.f, m = -1e30f;
  for (int i = start + sub; i < end; i += 4) {
    float v = fmaxf(agg[(size_t)i * 64 + c] + bc, 0.f);
    s += v;
    m = fmaxf(m, v);
  }
  __shared__ float ss[256], sm[256];
  ss[tid] = s; sm[tid] = m;
  __syncthreads();
  if (sub == 0) {
#pragma unroll
    for (int j = 1; j < 4; ++j) { s += ss[j * 64 + c]; m = fmaxf(m, sm[j * 64 + c]); }
    int cnt = end - start;
    float mean = cnt > 0 ? s / (float)cnt : 0.f;
    if (cnt == 0) m = 0.f;
    pooled[g * 128 + c] = mean;
    pooled[g * 128 + 64 + c] = m;
  }
}

__global__ __launch_bounds__(128) void k_head(const float* __restrict__ pooled,
                                              const float* __restrict__ Wout,
                                              const float* __restrict__ bout,
                                              float* __restrict__ out) {
  __shared__ float p[128];
  int g = blockIdx.x, tid = threadIdx.x;
  p[tid] = pooled[g * 128 + tid];
  __syncthreads();
  if (tid < NC) {
    float acc = bout[tid];
#pragma unroll 8
    for (int c = 0; c < 128; ++c) acc += p[c] * Wout[c * NC + tid];
    out[g * NC + tid] = acc;
  }
}

extern "C" void kernel_launch(void* const* d_in, const int* in_sizes, int n_in,
                              void* d_out, int out_size, void* d_ws, size_t ws_size,
                              hipStream_t stream) {
  const float* x     = (const float*)d_in[0];
  const int*   ei    = (const int*)d_in[1];
  const int*   batch = (const int*)d_in[2];
  const float* W0    = (const float*)d_in[3];
  const float* b0    = (const float*)d_in[4];
  const float* W1    = (const float*)d_in[5];
  const float* b1    = (const float*)d_in[6];
  const float* W2    = (const float*)d_in[7];
  const float* b2    = (const float*)d_in[8];
  const float* Wout  = (const float*)d_in[9];
  const float* bout  = (const float*)d_in[10];
  float* out = (float*)d_out;

  char* ws = (char*)d_ws;
  size_t off = 0;
  auto alloc = [&](size_t bytes) -> void* {
    void* p = ws + off;
    off = (off + bytes + 255) & ~(size_t)255;
    return p;
  };
  int*   deg     = (int*)alloc((size_t)NN * 4);
  int*   counter = (int*)alloc(4);
  float* dinv    = (float*)alloc((size_t)NN * 4);
  int*   rstart  = (int*)alloc((size_t)NN * 4);
  int*   cur     = (int*)alloc((size_t)NN * 4);
  int2*  csr     = (int2*)alloc((size_t)NE * 8);
  unsigned short* linbf = (unsigned short*)alloc((size_t)NN * 64 * 2);
  float* C       = (float*)alloc((size_t)NN * 64 * 4);
  float* D       = (float*)alloc((size_t)NN * 64 * 4);
  unsigned short* Wt0 = (unsigned short*)alloc(64 * 128 * 2);
  unsigned short* Wt1 = (unsigned short*)alloc(64 * 64 * 2);
  unsigned short* Wt2 = (unsigned short*)alloc(64 * 64 * 2);
  float* pooled  = (float*)alloc((size_t)NG * 128 * 4);

  // CSR build
  k_zero<<<(NN + 255) / 256, 256, 0, stream>>>(deg, NN);
  k_zero<<<1, 256, 0, stream>>>(counter, 1);
  k_deg<<<(NE + 255) / 256, 256, 0, stream>>>(ei + NE, deg);
  k_dinv<<<(NN + 255) / 256, 256, 0, stream>>>(deg, dinv);
  k_rowstart<<<(NN + 255) / 256, 256, 0, stream>>>(deg, rstart, cur, counter);
  k_fill<<<(NE + 255) / 256, 256, 0, stream>>>(ei, dinv, cur, csr);
  k_prepw<<<(128 * 64 + 255) / 256, 256, 0, stream>>>(W0, Wt0, 128);
  k_prepw<<<(64 * 64 + 255) / 256, 256, 0, stream>>>(W1, Wt1, 64);
  k_prepw<<<(64 * 64 + 255) / 256, 256, 0, stream>>>(W2, Wt2, 64);

  // layer 1
  k_gemm<128, false><<<2048, 256, 0, stream>>>(x, nullptr, Wt0, linbf);
  k_agg<<<(NN + 3) / 4, 256, 0, stream>>>(linbf, dinv, deg, rstart, csr, C);
  // layer 2
  k_gemm<64, true><<<2048, 256, 0, stream>>>(C, b0, Wt1, linbf);
  k_agg<<<(NN + 3) / 4, 256, 0, stream>>>(linbf, dinv, deg, rstart, csr, D);
  // layer 3
  k_gemm<64, true><<<2048, 256, 0, stream>>>(D, b1, Wt2, linbf);
  k_agg<<<(NN + 3) / 4, 256, 0, stream>>>(linbf, dinv, deg, rstart, csr, C);
  // pool + head
  k_pool<<<NG, 256, 0, stream>>>(C, b2, batch, pooled);
  k_head<<<NG, 128, 0, stream>>>(pooled, Wout, bout, out);
}

// Round 3
// 1159.685 us; speedup vs baseline: 1.4994x; 1.1668x over previous
//
#include <hip/hip_runtime.h>
#include <hip/hip_bf16.h>

#define NN 500000
#define NE 1250000
#define NF 128
#define NH 64
#define NC 10
#define NG 512

typedef __attribute__((ext_vector_type(8))) short short8;
typedef __attribute__((ext_vector_type(4))) float floatx4;

__device__ __forceinline__ unsigned short f2bf(float f) {
  unsigned u = __builtin_bit_cast(unsigned, f);
  u += 0x7FFFu + ((u >> 16) & 1u);
  return (unsigned short)(u >> 16);
}
__device__ __forceinline__ float bf2f(unsigned short u) {
  return __builtin_bit_cast(float, (unsigned)u << 16);
}

__global__ __launch_bounds__(256) void k_zero(int* __restrict__ p, int n) {
  int i = blockIdx.x * 256 + threadIdx.x;
  if (i < n) p[i] = 0;
}

__global__ __launch_bounds__(256) void k_deg(const int* __restrict__ dst, int* __restrict__ deg) {
  int e = blockIdx.x * 256 + threadIdx.x;
  if (e < NE) atomicAdd(&deg[dst[e]], 1);
}

__global__ __launch_bounds__(256) void k_dinv(const int* __restrict__ deg, float* __restrict__ dinv) {
  int i = blockIdx.x * 256 + threadIdx.x;
  if (i < NN) dinv[i] = rsqrtf((float)(deg[i] + 1));
}

// CSR row starts without global scan: wave-scan degrees, one atomic per wave.
__global__ __launch_bounds__(256) void k_rowstart(const int* __restrict__ deg,
                                                  int* __restrict__ row_start,
                                                  int* __restrict__ cur,
                                                  int* __restrict__ counter) {
  int i = blockIdx.x * 256 + threadIdx.x;
  int lane = threadIdx.x & 63;
  int d = (i < NN) ? deg[i] : 0;
  int incl = d;
#pragma unroll
  for (int off = 1; off < 64; off <<= 1) {
    int n = __shfl_up(incl, off, 64);
    if (lane >= off) incl += n;
  }
  int total = __shfl(incl, 63, 64);
  int base = 0;
  if (lane == 63) base = atomicAdd(counter, total);
  base = __shfl(base, 63, 64);
  if (i < NN) {
    int rs = base + incl - d;
    row_start[i] = rs;
    cur[i] = rs;
  }
}

// Bucket-fill CSR: packed (src, norm) per edge.
__global__ __launch_bounds__(256) void k_fill(const int* __restrict__ ei,
                                              const float* __restrict__ dinv,
                                              int* __restrict__ cur,
                                              int2* __restrict__ csr) {
  int e = blockIdx.x * 256 + threadIdx.x;
  if (e >= NE) return;
  int s = ei[e];
  int d = ei[NE + e];
  float nrm = dinv[s] * dinv[d];
  int idx = atomicAdd(&cur[d], 1);
  int2 v;
  v.x = s;
  v.y = __builtin_bit_cast(int, nrm);
  csr[idx] = v;
}

// W [K,64] row-major f32 -> Wt [64,K] bf16
__global__ __launch_bounds__(256) void k_prepw(const float* __restrict__ W,
                                               unsigned short* __restrict__ Wt, int K) {
  int idx = blockIdx.x * 256 + threadIdx.x;
  if (idx < K * 64) {
    int k = idx / 64, n = idx % 64;
    Wt[n * K + k] = f2bf(W[idx]);
  }
}

// Layer-1 GEMM: lin[M,64](bf16) = x[M,128](f32) @ W. 2 row-tiles per wave-iter for MLP.
__global__ __launch_bounds__(256) void k_gemm_f32(const float* __restrict__ Ain,
                                                  const unsigned short* __restrict__ Wt,
                                                  unsigned short* __restrict__ linbf) {
  constexpr int K = 128, KC = 4, SP = K + 8;
  __shared__ unsigned short Wl[64 * SP];
  int tid = threadIdx.x;
  for (int idx = tid * 8; idx < 64 * K; idx += 2048) {
    int n = idx / K, k = idx % K;
    *(short8*)&Wl[n * SP + k] = *(const short8*)&Wt[idx];
  }
  __syncthreads();

  int lane = tid & 63, wave = tid >> 6;
  int quad = lane >> 4, l16 = lane & 15;

  short8 bfrag[4][KC];
#pragma unroll
  for (int nt = 0; nt < 4; ++nt)
#pragma unroll
    for (int kc = 0; kc < KC; ++kc)
      bfrag[nt][kc] = *(const short8*)&Wl[(nt * 16 + l16) * SP + kc * 32 + quad * 8];

  const int ntiles = NN / 16;  // 31250
  for (int t0 = (blockIdx.x * 4 + wave) * 2; t0 < ntiles; t0 += gridDim.x * 8) {
    floatx4 acc[2][4];
    floatx4 araw[2][KC][2];
#pragma unroll
    for (int tt = 0; tt < 2; ++tt) {
      int arow = (t0 + tt) * 16 + l16;
      const float* Ab = Ain + (size_t)arow * K + quad * 8;
#pragma unroll
      for (int kc = 0; kc < KC; ++kc) {
        araw[tt][kc][0] = *(const floatx4*)(Ab + kc * 32);
        araw[tt][kc][1] = *(const floatx4*)(Ab + kc * 32 + 4);
      }
    }
#pragma unroll
    for (int tt = 0; tt < 2; ++tt) {
      floatx4 z = {0.f, 0.f, 0.f, 0.f};
#pragma unroll
      for (int nt = 0; nt < 4; ++nt) acc[tt][nt] = z;
#pragma unroll
      for (int kc = 0; kc < KC; ++kc) {
        short8 af;
#pragma unroll
        for (int q = 0; q < 4; ++q) {
          af[q] = (short)f2bf(araw[tt][kc][0][q]);
          af[q + 4] = (short)f2bf(araw[tt][kc][1][q]);
        }
#pragma unroll
        for (int nt = 0; nt < 4; ++nt)
          acc[tt][nt] = __builtin_amdgcn_mfma_f32_16x16x32_bf16(af, bfrag[nt][kc], acc[tt][nt], 0, 0, 0);
      }
#pragma unroll
      for (int i = 0; i < 4; ++i) {
        int r = (t0 + tt) * 16 + quad * 4 + i;
        unsigned short* lp = linbf + (size_t)r * 64 + l16;
#pragma unroll
        for (int nt = 0; nt < 4; ++nt) lp[nt * 16] = f2bf(acc[tt][nt][i]);
      }
    }
  }
}

// Layer-2/3 GEMM: lin[M,64](bf16) = h[M,64](bf16, pre-activated) @ W. Pure short8 loads.
__global__ __launch_bounds__(256) void k_gemm_bf(const unsigned short* __restrict__ Abf,
                                                 const unsigned short* __restrict__ Wt,
                                                 unsigned short* __restrict__ linbf) {
  constexpr int K = 64, KC = 2, SP = K + 8;
  __shared__ unsigned short Wl[64 * SP];
  int tid = threadIdx.x;
  for (int idx = tid * 8; idx < 64 * K; idx += 2048) {
    int n = idx / K, k = idx % K;
    *(short8*)&Wl[n * SP + k] = *(const short8*)&Wt[idx];
  }
  __syncthreads();

  int lane = tid & 63, wave = tid >> 6;
  int quad = lane >> 4, l16 = lane & 15;

  short8 bfrag[4][KC];
#pragma unroll
  for (int nt = 0; nt < 4; ++nt)
#pragma unroll
    for (int kc = 0; kc < KC; ++kc)
      bfrag[nt][kc] = *(const short8*)&Wl[(nt * 16 + l16) * SP + kc * 32 + quad * 8];

  const int ntiles = NN / 16;
  for (int t0 = (blockIdx.x * 4 + wave) * 2; t0 < ntiles; t0 += gridDim.x * 8) {
    short8 af[2][KC];
#pragma unroll
    for (int tt = 0; tt < 2; ++tt) {
      int arow = (t0 + tt) * 16 + l16;
#pragma unroll
      for (int kc = 0; kc < KC; ++kc)
        af[tt][kc] = *(const short8*)(Abf + (size_t)arow * 64 + kc * 32 + quad * 8);
    }
#pragma unroll
    for (int tt = 0; tt < 2; ++tt) {
      floatx4 z = {0.f, 0.f, 0.f, 0.f};
      floatx4 acc[4] = {z, z, z, z};
#pragma unroll
      for (int kc = 0; kc < KC; ++kc)
#pragma unroll
        for (int nt = 0; nt < 4; ++nt)
          acc[nt] = __builtin_amdgcn_mfma_f32_16x16x32_bf16(af[tt][kc], bfrag[nt][kc], acc[nt], 0, 0, 0);
#pragma unroll
      for (int i = 0; i < 4; ++i) {
        int r = (t0 + tt) * 16 + quad * 4 + i;
        unsigned short* lp = linbf + (size_t)r * 64 + l16;
#pragma unroll
        for (int nt = 0; nt < 4; ++nt) lp[nt * 16] = f2bf(acc[nt][i]);
      }
    }
  }
}

// Gather aggregation, wave-per-node, lane=feature, 4 edges per latency hop.
// h[r] = relu( lin[r]*dinv[r]^2 + sum_e lin[src_e]*norm_e + bias )  -> bf16
__global__ __launch_bounds__(256) void k_agg(const unsigned short* __restrict__ linbf,
                                             const float* __restrict__ dinv,
                                             const float* __restrict__ bias,
                                             const int* __restrict__ deg,
                                             const int* __restrict__ row_start,
                                             const int2* __restrict__ csr,
                                             unsigned short* __restrict__ hout) {
  int r = blockIdx.x * 4 + (threadIdx.x >> 6);
  if (r >= NN) return;
  int c = threadIdx.x & 63;
  float dv = dinv[r];
  float acc = bf2f(linbf[(size_t)r * 64 + c]) * dv * dv;
  int rs = row_start[r];
  int dg = deg[r];
  for (int j = 0; j < dg; j += 4) {
    int2 e0 = csr[rs + j];        // +4-entry pad keeps these in-bounds
    int2 e1 = csr[rs + j + 1];
    int2 e2 = csr[rs + j + 2];
    int2 e3 = csr[rs + j + 3];
    int rem = dg - j;
    int s0 = e0.x;
    int s1 = rem > 1 ? e1.x : r;
    int s2 = rem > 2 ? e2.x : r;
    int s3 = rem > 3 ? e3.x : r;
    float n0 = __builtin_bit_cast(float, e0.y);
    float n1 = rem > 1 ? __builtin_bit_cast(float, e1.y) : 0.f;
    float n2 = rem > 2 ? __builtin_bit_cast(float, e2.y) : 0.f;
    float n3 = rem > 3 ? __builtin_bit_cast(float, e3.y) : 0.f;
    float g0 = bf2f(linbf[(size_t)s0 * 64 + c]);
    float g1 = bf2f(linbf[(size_t)s1 * 64 + c]);
    float g2 = bf2f(linbf[(size_t)s2 * 64 + c]);
    float g3 = bf2f(linbf[(size_t)s3 * 64 + c]);
    acc = fmaf(n0, g0, acc);
    acc = fmaf(n1, g1, acc);
    acc = fmaf(n2, g2, acc);
    acc = fmaf(n3, g3, acc);
  }
  hout[(size_t)r * 64 + c] = f2bf(fmaxf(acc + bias[c], 0.f));
}

// one block per graph; batch sorted -> binary search; h already bias+relu'd (bf16)
__global__ __launch_bounds__(256) void k_pool(const unsigned short* __restrict__ h,
                                              const int* __restrict__ batch,
                                              float* __restrict__ pooled) {
  int g = blockIdx.x;
  int tid = threadIdx.x;
  int c = tid & 63, sub = tid >> 6;

  int lo = 0, hi = NN;
  while (lo < hi) { int mid = (lo + hi) >> 1; if (batch[mid] < g) lo = mid + 1; else hi = mid; }
  int start = lo;
  lo = 0; hi = NN;
  while (lo < hi) { int mid = (lo + hi) >> 1; if (batch[mid] < g + 1) lo = mid + 1; else hi = mid; }
  int end = lo;

  float s = 0.f, m = 0.f;  // relu output >= 0, so max-identity 0 is exact; empty graph -> 0 matches ref
  for (int i = start + sub; i < end; i += 4) {
    float v = bf2f(h[(size_t)i * 64 + c]);
    s += v;
    m = fmaxf(m, v);
  }
  __shared__ float ss[256], sm[256];
  ss[tid] = s; sm[tid] = m;
  __syncthreads();
  if (sub == 0) {
#pragma unroll
    for (int j = 1; j < 4; ++j) { s += ss[j * 64 + c]; m = fmaxf(m, sm[j * 64 + c]); }
    int cnt = end - start;
    float mean = cnt > 0 ? s / (float)cnt : 0.f;
    pooled[g * 128 + c] = mean;
    pooled[g * 128 + 64 + c] = m;
  }
}

__global__ __launch_bounds__(128) void k_head(const float* __restrict__ pooled,
                                              const float* __restrict__ Wout,
                                              const float* __restrict__ bout,
                                              float* __restrict__ out) {
  __shared__ float p[128];
  int g = blockIdx.x, tid = threadIdx.x;
  p[tid] = pooled[g * 128 + tid];
  __syncthreads();
  if (tid < NC) {
    float acc = bout[tid];
#pragma unroll 8
    for (int c = 0; c < 128; ++c) acc += p[c] * Wout[c * NC + tid];
    out[g * NC + tid] = acc;
  }
}

extern "C" void kernel_launch(void* const* d_in, const int* in_sizes, int n_in,
                              void* d_out, int out_size, void* d_ws, size_t ws_size,
                              hipStream_t stream) {
  const float* x     = (const float*)d_in[0];
  const int*   ei    = (const int*)d_in[1];
  const int*   batch = (const int*)d_in[2];
  const float* W0    = (const float*)d_in[3];
  const float* b0    = (const float*)d_in[4];
  const float* W1    = (const float*)d_in[5];
  const float* b1    = (const float*)d_in[6];
  const float* W2    = (const float*)d_in[7];
  const float* b2    = (const float*)d_in[8];
  const float* Wout  = (const float*)d_in[9];
  const float* bout  = (const float*)d_in[10];
  float* out = (float*)d_out;

  char* ws = (char*)d_ws;
  size_t off = 0;
  auto alloc = [&](size_t bytes) -> void* {
    void* p = ws + off;
    off = (off + bytes + 255) & ~(size_t)255;
    return p;
  };
  int*   deg     = (int*)alloc((size_t)NN * 4);
  int*   counter = (int*)alloc(4);
  float* dinv    = (float*)alloc((size_t)NN * 4);
  int*   rstart  = (int*)alloc((size_t)NN * 4);
  int*   cur     = (int*)alloc((size_t)NN * 4);
  int2*  csr     = (int2*)alloc(((size_t)NE + 4) * 8);  // +4 pad for unrolled reads
  unsigned short* linbf = (unsigned short*)alloc((size_t)NN * 64 * 2);
  unsigned short* H1    = (unsigned short*)alloc((size_t)NN * 64 * 2);
  unsigned short* H2    = (unsigned short*)alloc((size_t)NN * 64 * 2);
  unsigned short* Wt0 = (unsigned short*)alloc(64 * 128 * 2);
  unsigned short* Wt1 = (unsigned short*)alloc(64 * 64 * 2);
  unsigned short* Wt2 = (unsigned short*)alloc(64 * 64 * 2);
  float* pooled  = (float*)alloc((size_t)NG * 128 * 4);

  // CSR build
  k_zero<<<(NN + 255) / 256, 256, 0, stream>>>(deg, NN);
  k_zero<<<1, 256, 0, stream>>>(counter, 1);
  k_deg<<<(NE + 255) / 256, 256, 0, stream>>>(ei + NE, deg);
  k_dinv<<<(NN + 255) / 256, 256, 0, stream>>>(deg, dinv);
  k_rowstart<<<(NN + 255) / 256, 256, 0, stream>>>(deg, rstart, cur, counter);
  k_fill<<<(NE + 255) / 256, 256, 0, stream>>>(ei, dinv, cur, csr);
  k_prepw<<<(128 * 64 + 255) / 256, 256, 0, stream>>>(W0, Wt0, 128);
  k_prepw<<<(64 * 64 + 255) / 256, 256, 0, stream>>>(W1, Wt1, 64);
  k_prepw<<<(64 * 64 + 255) / 256, 256, 0, stream>>>(W2, Wt2, 64);

  // layer 1
  k_gemm_f32<<<2048, 256, 0, stream>>>(x, Wt0, linbf);
  k_agg<<<(NN + 3) / 4, 256, 0, stream>>>(linbf, dinv, b0, deg, rstart, csr, H1);
  // layer 2
  k_gemm_bf<<<2048, 256, 0, stream>>>(H1, Wt1, linbf);
  k_agg<<<(NN + 3) / 4, 256, 0, stream>>>(linbf, dinv, b1, deg, rstart, csr, H2);
  // layer 3
  k_gemm_bf<<<2048, 256, 0, stream>>>(H2, Wt2, linbf);
  k_agg<<<(NN + 3) / 4, 256, 0, stream>>>(linbf, dinv, b2, deg, rstart, csr, H1);
  // pool + head
  k_pool<<<NG, 256, 0, stream>>>(H1, batch, pooled);
  k_head<<<NG, 128, 0, stream>>>(pooled, Wout, bout, out);
}

// Round 4
// 978.368 us; speedup vs baseline: 1.7773x; 1.1853x over previous
//
#include <hip/hip_runtime.h>
#include <hip/hip_bf16.h>

#define NN 500000
#define NE 1250000
#define NF 128
#define NH 64
#define NC 10
#define NG 512
#define ELLW 8

typedef __attribute__((ext_vector_type(8))) short short8;
typedef __attribute__((ext_vector_type(4))) float floatx4;

__device__ __forceinline__ unsigned short f2bf(float f) {
  unsigned u = __builtin_bit_cast(unsigned, f);
  u += 0x7FFFu + ((u >> 16) & 1u);
  return (unsigned short)(u >> 16);
}
__device__ __forceinline__ float bf2f(unsigned short u) {
  return __builtin_bit_cast(float, (unsigned)u << 16);
}

__global__ __launch_bounds__(256) void k_zero(int* __restrict__ p, int n) {
  int i = blockIdx.x * 256 + threadIdx.x;
  if (i < n) p[i] = 0;
}

__global__ __launch_bounds__(256) void k_deg(const int* __restrict__ dst, int* __restrict__ deg) {
  int e = blockIdx.x * 256 + threadIdx.x;
  if (e < NE) atomicAdd(&deg[dst[e]], 1);
}

// dinv + overflow-degree in one pass
__global__ __launch_bounds__(256) void k_dinv(const int* __restrict__ deg,
                                              float* __restrict__ dinv,
                                              int* __restrict__ odeg) {
  int i = blockIdx.x * 256 + threadIdx.x;
  if (i < NN) {
    int d = deg[i];
    dinv[i] = rsqrtf((float)(d + 1));
    odeg[i] = d > ELLW ? d - ELLW : 0;
  }
}

// ELL pad init: every slot = (self, 0) -> unconditional pad gathers are harmless
__global__ __launch_bounds__(256) void k_ellinit(int2* __restrict__ ell) {
  int i = blockIdx.x * 256 + threadIdx.x;
  if (i < NN * ELLW) {
    int2 v; v.x = i >> 3; v.y = 0;
    ell[i] = v;
  }
}

// overflow CSR row starts: wave-scan, one atomic per wave (row order arbitrary)
__global__ __launch_bounds__(256) void k_rowstart(const int* __restrict__ deg,
                                                  int* __restrict__ row_start,
                                                  int* __restrict__ counter) {
  int i = blockIdx.x * 256 + threadIdx.x;
  int lane = threadIdx.x & 63;
  int d = (i < NN) ? deg[i] : 0;
  int incl = d;
#pragma unroll
  for (int off = 1; off < 64; off <<= 1) {
    int n = __shfl_up(incl, off, 64);
    if (lane >= off) incl += n;
  }
  int total = __shfl(incl, 63, 64);
  int base = 0;
  if (lane == 63) base = atomicAdd(counter, total);
  base = __shfl(base, 63, 64);
  if (i < NN) row_start[i] = base + incl - d;
}

// Bucket-fill: slot<ELLW -> ELL row, else overflow CSR
__global__ __launch_bounds__(256) void k_fill(const int* __restrict__ ei,
                                              const float* __restrict__ dinv,
                                              int* __restrict__ cur,
                                              int2* __restrict__ ell,
                                              const int* __restrict__ ostart,
                                              int2* __restrict__ ovf) {
  int e = blockIdx.x * 256 + threadIdx.x;
  if (e >= NE) return;
  int s = ei[e];
  int d = ei[NE + e];
  float nrm = dinv[s] * dinv[d];
  int slot = atomicAdd(&cur[d], 1);
  int2 v;
  v.x = s;
  v.y = __builtin_bit_cast(int, nrm);
  if (slot < ELLW) ell[(size_t)d * ELLW + slot] = v;
  else ovf[ostart[d] + slot - ELLW] = v;
}

// W [K,64] row-major f32 -> Wt [64,K] bf16
__global__ __launch_bounds__(256) void k_prepw(const float* __restrict__ W,
                                               unsigned short* __restrict__ Wt, int K) {
  int idx = blockIdx.x * 256 + threadIdx.x;
  if (idx < K * 64) {
    int k = idx / 64, n = idx % 64;
    Wt[n * K + k] = f2bf(W[idx]);
  }
}

// Layer-1 GEMM: lin[M,64](bf16) = x[M,128](f32) @ W
__global__ __launch_bounds__(256) void k_gemm_f32(const float* __restrict__ Ain,
                                                  const unsigned short* __restrict__ Wt,
                                                  unsigned short* __restrict__ linbf) {
  constexpr int K = 128, KC = 4, SP = K + 8;
  __shared__ unsigned short Wl[64 * SP];
  int tid = threadIdx.x;
  for (int idx = tid * 8; idx < 64 * K; idx += 2048) {
    int n = idx / K, k = idx % K;
    *(short8*)&Wl[n * SP + k] = *(const short8*)&Wt[idx];
  }
  __syncthreads();

  int lane = tid & 63, wave = tid >> 6;
  int quad = lane >> 4, l16 = lane & 15;

  short8 bfrag[4][KC];
#pragma unroll
  for (int nt = 0; nt < 4; ++nt)
#pragma unroll
    for (int kc = 0; kc < KC; ++kc)
      bfrag[nt][kc] = *(const short8*)&Wl[(nt * 16 + l16) * SP + kc * 32 + quad * 8];

  const int ntiles = NN / 16;  // 31250
  for (int t0 = (blockIdx.x * 4 + wave) * 2; t0 < ntiles; t0 += gridDim.x * 8) {
    floatx4 acc[2][4];
    floatx4 araw[2][KC][2];
#pragma unroll
    for (int tt = 0; tt < 2; ++tt) {
      int arow = (t0 + tt) * 16 + l16;
      const float* Ab = Ain + (size_t)arow * K + quad * 8;
#pragma unroll
      for (int kc = 0; kc < KC; ++kc) {
        araw[tt][kc][0] = *(const floatx4*)(Ab + kc * 32);
        araw[tt][kc][1] = *(const floatx4*)(Ab + kc * 32 + 4);
      }
    }
#pragma unroll
    for (int tt = 0; tt < 2; ++tt) {
      floatx4 z = {0.f, 0.f, 0.f, 0.f};
#pragma unroll
      for (int nt = 0; nt < 4; ++nt) acc[tt][nt] = z;
#pragma unroll
      for (int kc = 0; kc < KC; ++kc) {
        short8 af;
#pragma unroll
        for (int q = 0; q < 4; ++q) {
          af[q] = (short)f2bf(araw[tt][kc][0][q]);
          af[q + 4] = (short)f2bf(araw[tt][kc][1][q]);
        }
#pragma unroll
        for (int nt = 0; nt < 4; ++nt)
          acc[tt][nt] = __builtin_amdgcn_mfma_f32_16x16x32_bf16(af, bfrag[nt][kc], acc[tt][nt], 0, 0, 0);
      }
#pragma unroll
      for (int i = 0; i < 4; ++i) {
        int r = (t0 + tt) * 16 + quad * 4 + i;
        unsigned short* lp = linbf + (size_t)r * 64 + l16;
#pragma unroll
        for (int nt = 0; nt < 4; ++nt) lp[nt * 16] = f2bf(acc[tt][nt][i]);
      }
    }
  }
}

// Layer-2/3 GEMM: lin[M,64](bf16) = h[M,64](bf16) @ W
__global__ __launch_bounds__(256) void k_gemm_bf(const unsigned short* __restrict__ Abf,
                                                 const unsigned short* __restrict__ Wt,
                                                 unsigned short* __restrict__ linbf) {
  constexpr int K = 64, KC = 2, SP = K + 8;
  __shared__ unsigned short Wl[64 * SP];
  int tid = threadIdx.x;
  for (int idx = tid * 8; idx < 64 * K; idx += 2048) {
    int n = idx / K, k = idx % K;
    *(short8*)&Wl[n * SP + k] = *(const short8*)&Wt[idx];
  }
  __syncthreads();

  int lane = tid & 63, wave = tid >> 6;
  int quad = lane >> 4, l16 = lane & 15;

  short8 bfrag[4][KC];
#pragma unroll
  for (int nt = 0; nt < 4; ++nt)
#pragma unroll
    for (int kc = 0; kc < KC; ++kc)
      bfrag[nt][kc] = *(const short8*)&Wl[(nt * 16 + l16) * SP + kc * 32 + quad * 8];

  const int ntiles = NN / 16;
  for (int t0 = (blockIdx.x * 4 + wave) * 2; t0 < ntiles; t0 += gridDim.x * 8) {
    short8 af[2][KC];
#pragma unroll
    for (int tt = 0; tt < 2; ++tt) {
      int arow = (t0 + tt) * 16 + l16;
#pragma unroll
      for (int kc = 0; kc < KC; ++kc)
        af[tt][kc] = *(const short8*)(Abf + (size_t)arow * 64 + kc * 32 + quad * 8);
    }
#pragma unroll
    for (int tt = 0; tt < 2; ++tt) {
      floatx4 z = {0.f, 0.f, 0.f, 0.f};
      floatx4 acc[4] = {z, z, z, z};
#pragma unroll
      for (int kc = 0; kc < KC; ++kc)
#pragma unroll
        for (int nt = 0; nt < 4; ++nt)
          acc[nt] = __builtin_amdgcn_mfma_f32_16x16x32_bf16(af[tt][kc], bfrag[nt][kc], acc[nt], 0, 0, 0);
#pragma unroll
      for (int i = 0; i < 4; ++i) {
        int r = (t0 + tt) * 16 + quad * 4 + i;
        unsigned short* lp = linbf + (size_t)r * 64 + l16;
#pragma unroll
        for (int nt = 0; nt < 4; ++nt) lp[nt * 16] = f2bf(acc[nt][i]);
      }
    }
  }
}

// ELL gather aggregation, wave-per-node, lane=feature. 2 dependent load hops:
// hop1 = {ell row (64B broadcast), deg, dinv, own lin row, bias}; hop2 = gathers.
// h[r] = relu( lin[r]*dinv^2 + sum lin[src]*norm + bias ) -> bf16
__global__ __launch_bounds__(256) void k_agg(const unsigned short* __restrict__ linbf,
                                             const float* __restrict__ dinv,
                                             const float* __restrict__ bias,
                                             const int* __restrict__ deg,
                                             const int2* __restrict__ ell,
                                             const int* __restrict__ ostart,
                                             const int2* __restrict__ ovf,
                                             unsigned short* __restrict__ hout) {
  int r = blockIdx.x * 4 + (threadIdx.x >> 6);
  if (r >= NN) return;
  int c = threadIdx.x & 63;
  const int4* ellv = (const int4*)(ell + (size_t)r * ELLW);
  int4 q0 = ellv[0];  // entries 0,1
  int4 q1 = ellv[1];  // entries 2,3
  int4 q2 = ellv[2];  // entries 4,5
  int4 q3 = ellv[3];  // entries 6,7
  int dg = deg[r];
  float dv = dinv[r];
  float bc = bias[c];
  float own = bf2f(linbf[(size_t)r * 64 + c]);
  float acc = own * dv * dv;

  // entries 0..3 unconditional (pads are (r,0) -> self-gather * 0)
  float g0 = bf2f(linbf[(size_t)q0.x * 64 + c]);
  float g1 = bf2f(linbf[(size_t)q0.z * 64 + c]);
  float g2 = bf2f(linbf[(size_t)q1.x * 64 + c]);
  float g3 = bf2f(linbf[(size_t)q1.z * 64 + c]);
  acc = fmaf(__builtin_bit_cast(float, q0.y), g0, acc);
  acc = fmaf(__builtin_bit_cast(float, q0.w), g1, acc);
  acc = fmaf(__builtin_bit_cast(float, q1.y), g2, acc);
  acc = fmaf(__builtin_bit_cast(float, q1.w), g3, acc);

  if (dg > 4) {
    float g4 = bf2f(linbf[(size_t)q2.x * 64 + c]);
    float g5 = bf2f(linbf[(size_t)q2.z * 64 + c]);
    float g6 = bf2f(linbf[(size_t)q3.x * 64 + c]);
    float g7 = bf2f(linbf[(size_t)q3.z * 64 + c]);
    acc = fmaf(__builtin_bit_cast(float, q2.y), g4, acc);
    acc = fmaf(__builtin_bit_cast(float, q2.w), g5, acc);
    acc = fmaf(__builtin_bit_cast(float, q3.y), g6, acc);
    acc = fmaf(__builtin_bit_cast(float, q3.w), g7, acc);
  }

  if (dg > ELLW) {  // rare (P ~ 1e-3): overflow CSR tail
    int rs = ostart[r];
    int on = dg - ELLW;
    for (int j = 0; j < on; j += 4) {
      int2 e0 = ovf[rs + j];
      int2 e1 = ovf[rs + j + 1];
      int2 e2 = ovf[rs + j + 2];
      int2 e3 = ovf[rs + j + 3];
      int rem = on - j;
      float n0 = __builtin_bit_cast(float, e0.y);
      float n1 = rem > 1 ? __builtin_bit_cast(float, e1.y) : 0.f;
      float n2 = rem > 2 ? __builtin_bit_cast(float, e2.y) : 0.f;
      float n3 = rem > 3 ? __builtin_bit_cast(float, e3.y) : 0.f;
      int s0 = e0.x;
      int s1 = rem > 1 ? e1.x : r;
      int s2 = rem > 2 ? e2.x : r;
      int s3 = rem > 3 ? e3.x : r;
      acc = fmaf(n0, bf2f(linbf[(size_t)s0 * 64 + c]), acc);
      acc = fmaf(n1, bf2f(linbf[(size_t)s1 * 64 + c]), acc);
      acc = fmaf(n2, bf2f(linbf[(size_t)s2 * 64 + c]), acc);
      acc = fmaf(n3, bf2f(linbf[(size_t)s3 * 64 + c]), acc);
    }
  }
  hout[(size_t)r * 64 + c] = f2bf(fmaxf(acc + bc, 0.f));
}

// one block per graph; 8-way unrolled row stream for MLP
__global__ __launch_bounds__(256) void k_pool(const unsigned short* __restrict__ h,
                                              const int* __restrict__ batch,
                                              float* __restrict__ pooled) {
  int g = blockIdx.x;
  int tid = threadIdx.x;
  int c = tid & 63, sub = tid >> 6;

  int lo = 0, hi = NN;
  while (lo < hi) { int mid = (lo + hi) >> 1; if (batch[mid] < g) lo = mid + 1; else hi = mid; }
  int start = lo;
  lo = 0; hi = NN;
  while (lo < hi) { int mid = (lo + hi) >> 1; if (batch[mid] < g + 1) lo = mid + 1; else hi = mid; }
  int end = lo;

  float s = 0.f, m = 0.f;  // relu >= 0 so 0 is a valid max identity; empty graph -> 0 matches ref
  int i = start + sub;
  for (; i + 28 < end; i += 32) {
    float v0 = bf2f(h[(size_t)(i)      * 64 + c]);
    float v1 = bf2f(h[(size_t)(i + 4)  * 64 + c]);
    float v2 = bf2f(h[(size_t)(i + 8)  * 64 + c]);
    float v3 = bf2f(h[(size_t)(i + 12) * 64 + c]);
    float v4 = bf2f(h[(size_t)(i + 16) * 64 + c]);
    float v5 = bf2f(h[(size_t)(i + 20) * 64 + c]);
    float v6 = bf2f(h[(size_t)(i + 24) * 64 + c]);
    float v7 = bf2f(h[(size_t)(i + 28) * 64 + c]);
    s += v0 + v1 + v2 + v3 + v4 + v5 + v6 + v7;
    m = fmaxf(m, fmaxf(fmaxf(fmaxf(v0, v1), fmaxf(v2, v3)),
                       fmaxf(fmaxf(v4, v5), fmaxf(v6, v7))));
  }
  for (; i < end; i += 4) {
    float v = bf2f(h[(size_t)i * 64 + c]);
    s += v;
    m = fmaxf(m, v);
  }
  __shared__ float ss[256], sm[256];
  ss[tid] = s; sm[tid] = m;
  __syncthreads();
  if (sub == 0) {
#pragma unroll
    for (int j = 1; j < 4; ++j) { s += ss[j * 64 + c]; m = fmaxf(m, sm[j * 64 + c]); }
    int cnt = end - start;
    float mean = cnt > 0 ? s / (float)cnt : 0.f;
    pooled[g * 128 + c] = mean;
    pooled[g * 128 + 64 + c] = m;
  }
}

__global__ __launch_bounds__(128) void k_head(const float* __restrict__ pooled,
                                              const float* __restrict__ Wout,
                                              const float* __restrict__ bout,
                                              float* __restrict__ out) {
  __shared__ float p[128];
  int g = blockIdx.x, tid = threadIdx.x;
  p[tid] = pooled[g * 128 + tid];
  __syncthreads();
  if (tid < NC) {
    float acc = bout[tid];
#pragma unroll 8
    for (int c = 0; c < 128; ++c) acc += p[c] * Wout[c * NC + tid];
    out[g * NC + tid] = acc;
  }
}

extern "C" void kernel_launch(void* const* d_in, const int* in_sizes, int n_in,
                              void* d_out, int out_size, void* d_ws, size_t ws_size,
                              hipStream_t stream) {
  const float* x     = (const float*)d_in[0];
  const int*   ei    = (const int*)d_in[1];
  const int*   batch = (const int*)d_in[2];
  const float* W0    = (const float*)d_in[3];
  const float* b0    = (const float*)d_in[4];
  const float* W1    = (const float*)d_in[5];
  const float* b1    = (const float*)d_in[6];
  const float* W2    = (const float*)d_in[7];
  const float* b2    = (const float*)d_in[8];
  const float* Wout  = (const float*)d_in[9];
  const float* bout  = (const float*)d_in[10];
  float* out = (float*)d_out;

  char* ws = (char*)d_ws;
  size_t off = 0;
  auto alloc = [&](size_t bytes) -> void* {
    void* p = ws + off;
    off = (off + bytes + 255) & ~(size_t)255;
    return p;
  };
  int*   deg     = (int*)alloc((size_t)NN * 4);
  int*   odeg    = (int*)alloc((size_t)NN * 4);
  int*   counter = (int*)alloc(4);
  float* dinv    = (float*)alloc((size_t)NN * 4);
  int*   ostart  = (int*)alloc((size_t)NN * 4);
  int*   cur     = (int*)alloc((size_t)NN * 4);
  int2*  ell     = (int2*)alloc((size_t)NN * ELLW * 8);   // 32 MB
  int2*  ovf     = (int2*)alloc(((size_t)NE + 4) * 8);
  unsigned short* linbf = (unsigned short*)alloc((size_t)NN * 64 * 2);
  unsigned short* H1    = (unsigned short*)alloc((size_t)NN * 64 * 2);
  unsigned short* H2    = (unsigned short*)alloc((size_t)NN * 64 * 2);
  unsigned short* Wt0 = (unsigned short*)alloc(64 * 128 * 2);
  unsigned short* Wt1 = (unsigned short*)alloc(64 * 64 * 2);
  unsigned short* Wt2 = (unsigned short*)alloc(64 * 64 * 2);
  float* pooled  = (float*)alloc((size_t)NG * 128 * 4);

  // graph prep
  k_zero<<<(NN + 255) / 256, 256, 0, stream>>>(deg, NN);
  k_zero<<<(NN + 255) / 256, 256, 0, stream>>>(cur, NN);
  k_zero<<<1, 256, 0, stream>>>(counter, 1);
  k_deg<<<(NE + 255) / 256, 256, 0, stream>>>(ei + NE, deg);
  k_dinv<<<(NN + 255) / 256, 256, 0, stream>>>(deg, dinv, odeg);
  k_rowstart<<<(NN + 255) / 256, 256, 0, stream>>>(odeg, ostart, counter);
  k_ellinit<<<(NN * ELLW + 255) / 256, 256, 0, stream>>>(ell);
  k_fill<<<(NE + 255) / 256, 256, 0, stream>>>(ei, dinv, cur, ell, ostart, ovf);
  k_prepw<<<(128 * 64 + 255) / 256, 256, 0, stream>>>(W0, Wt0, 128);
  k_prepw<<<(64 * 64 + 255) / 256, 256, 0, stream>>>(W1, Wt1, 64);
  k_prepw<<<(64 * 64 + 255) / 256, 256, 0, stream>>>(W2, Wt2, 64);

  // layer 1
  k_gemm_f32<<<2048, 256, 0, stream>>>(x, Wt0, linbf);
  k_agg<<<(NN + 3) / 4, 256, 0, stream>>>(linbf, dinv, b0, deg, ell, ostart, ovf, H1);
  // layer 2
  k_gemm_bf<<<2048, 256, 0, stream>>>(H1, Wt1, linbf);
  k_agg<<<(NN + 3) / 4, 256, 0, stream>>>(linbf, dinv, b1, deg, ell, ostart, ovf, H2);
  // layer 3
  k_gemm_bf<<<2048, 256, 0, stream>>>(H2, Wt2, linbf);
  k_agg<<<(NN + 3) / 4, 256, 0, stream>>>(linbf, dinv, b2, deg, ell, ostart, ovf, H1);
  // pool + head
  k_pool<<<NG, 256, 0, stream>>>(H1, batch, pooled);
  k_head<<<NG, 128, 0, stream>>>(pooled, Wout, bout, out);
}

// Round 5
// 974.071 us; speedup vs baseline: 1.7852x; 1.0044x over previous
//
#include <hip/hip_runtime.h>
#include <hip/hip_bf16.h>

#define NN 500000
#define NE 1250000
#define NF 128
#define NH 64
#define NC 10
#define NG 512
#define ELLW 8

typedef __attribute__((ext_vector_type(8))) short short8;
typedef __attribute__((ext_vector_type(4))) float floatx4;

__device__ __forceinline__ unsigned short f2bf(float f) {
  unsigned u = __builtin_bit_cast(unsigned, f);
  u += 0x7FFFu + ((u >> 16) & 1u);
  return (unsigned short)(u >> 16);
}
__device__ __forceinline__ float bf2f(unsigned short u) {
  return __builtin_bit_cast(float, (unsigned)u << 16);
}
__device__ __forceinline__ float asf(int i) { return __builtin_bit_cast(float, i); }

// zero deg+cur+counter in one launch
__global__ __launch_bounds__(256) void k_init(int* __restrict__ deg, int* __restrict__ cur,
                                              int* __restrict__ counter) {
  int i = blockIdx.x * 256 + threadIdx.x;
  if (i < NN) { deg[i] = 0; cur[i] = 0; }
  if (i == 0) *counter = 0;
}

__global__ __launch_bounds__(256) void k_deg(const int* __restrict__ dst, int* __restrict__ deg) {
  int e = blockIdx.x * 256 + threadIdx.x;
  if (e < NE) atomicAdd(&deg[dst[e]], 1);
}

__global__ __launch_bounds__(256) void k_dinv(const int* __restrict__ deg,
                                              float* __restrict__ dinv,
                                              int* __restrict__ odeg) {
  int i = blockIdx.x * 256 + threadIdx.x;
  if (i < NN) {
    int d = deg[i];
    dinv[i] = rsqrtf((float)(d + 1));
    odeg[i] = d > ELLW ? d - ELLW : 0;
  }
}

// ELL pad init: every slot = (self, 0) -> unconditional pad gathers are harmless
__global__ __launch_bounds__(256) void k_ellinit(int2* __restrict__ ell) {
  int i = blockIdx.x * 256 + threadIdx.x;
  if (i < NN * ELLW) {
    int2 v; v.x = i >> 3; v.y = 0;
    ell[i] = v;
  }
}

// overflow CSR row starts: wave-scan, one atomic per wave (row order arbitrary)
__global__ __launch_bounds__(256) void k_rowstart(const int* __restrict__ deg,
                                                  int* __restrict__ row_start,
                                                  int* __restrict__ counter) {
  int i = blockIdx.x * 256 + threadIdx.x;
  int lane = threadIdx.x & 63;
  int d = (i < NN) ? deg[i] : 0;
  int incl = d;
#pragma unroll
  for (int off = 1; off < 64; off <<= 1) {
    int n = __shfl_up(incl, off, 64);
    if (lane >= off) incl += n;
  }
  int total = __shfl(incl, 63, 64);
  int base = 0;
  if (lane == 63) base = atomicAdd(counter, total);
  base = __shfl(base, 63, 64);
  if (i < NN) row_start[i] = base + incl - d;
}

// Bucket-fill: slot<ELLW -> ELL row, else overflow CSR
__global__ __launch_bounds__(256) void k_fill(const int* __restrict__ ei,
                                              const float* __restrict__ dinv,
                                              int* __restrict__ cur,
                                              int2* __restrict__ ell,
                                              const int* __restrict__ ostart,
                                              int2* __restrict__ ovf) {
  int e = blockIdx.x * 256 + threadIdx.x;
  if (e >= NE) return;
  int s = ei[e];
  int d = ei[NE + e];
  float nrm = dinv[s] * dinv[d];
  int slot = atomicAdd(&cur[d], 1);
  int2 v;
  v.x = s;
  v.y = __builtin_bit_cast(int, nrm);
  if (slot < ELLW) ell[(size_t)d * ELLW + slot] = v;
  else ovf[ostart[d] + slot - ELLW] = v;
}

// W [K,64] row-major f32 -> Wt [64,K] bf16
__global__ __launch_bounds__(256) void k_prepw(const float* __restrict__ W,
                                               unsigned short* __restrict__ Wt, int K) {
  int idx = blockIdx.x * 256 + threadIdx.x;
  if (idx < K * 64) {
    int k = idx / 64, n = idx % 64;
    Wt[n * K + k] = f2bf(W[idx]);
  }
}

// Layer-1 GEMM: lin[M,64](bf16) = x[M,128](f32) @ W
__global__ __launch_bounds__(256) void k_gemm_f32(const float* __restrict__ Ain,
                                                  const unsigned short* __restrict__ Wt,
                                                  unsigned short* __restrict__ linbf) {
  constexpr int K = 128, KC = 4, SP = K + 8;
  __shared__ unsigned short Wl[64 * SP];
  int tid = threadIdx.x;
  for (int idx = tid * 8; idx < 64 * K; idx += 2048) {
    int n = idx / K, k = idx % K;
    *(short8*)&Wl[n * SP + k] = *(const short8*)&Wt[idx];
  }
  __syncthreads();

  int lane = tid & 63, wave = tid >> 6;
  int quad = lane >> 4, l16 = lane & 15;

  short8 bfrag[4][KC];
#pragma unroll
  for (int nt = 0; nt < 4; ++nt)
#pragma unroll
    for (int kc = 0; kc < KC; ++kc)
      bfrag[nt][kc] = *(const short8*)&Wl[(nt * 16 + l16) * SP + kc * 32 + quad * 8];

  const int ntiles = NN / 16;  // 31250
  for (int t0 = (blockIdx.x * 4 + wave) * 2; t0 < ntiles; t0 += gridDim.x * 8) {
    floatx4 acc[2][4];
    floatx4 araw[2][KC][2];
#pragma unroll
    for (int tt = 0; tt < 2; ++tt) {
      int arow = (t0 + tt) * 16 + l16;
      const float* Ab = Ain + (size_t)arow * K + quad * 8;
#pragma unroll
      for (int kc = 0; kc < KC; ++kc) {
        araw[tt][kc][0] = *(const floatx4*)(Ab + kc * 32);
        araw[tt][kc][1] = *(const floatx4*)(Ab + kc * 32 + 4);
      }
    }
#pragma unroll
    for (int tt = 0; tt < 2; ++tt) {
      floatx4 z = {0.f, 0.f, 0.f, 0.f};
#pragma unroll
      for (int nt = 0; nt < 4; ++nt) acc[tt][nt] = z;
#pragma unroll
      for (int kc = 0; kc < KC; ++kc) {
        short8 af;
#pragma unroll
        for (int q = 0; q < 4; ++q) {
          af[q] = (short)f2bf(araw[tt][kc][0][q]);
          af[q + 4] = (short)f2bf(araw[tt][kc][1][q]);
        }
#pragma unroll
        for (int nt = 0; nt < 4; ++nt)
          acc[tt][nt] = __builtin_amdgcn_mfma_f32_16x16x32_bf16(af, bfrag[nt][kc], acc[tt][nt], 0, 0, 0);
      }
#pragma unroll
      for (int i = 0; i < 4; ++i) {
        int r = (t0 + tt) * 16 + quad * 4 + i;
        unsigned short* lp = linbf + (size_t)r * 64 + l16;
#pragma unroll
        for (int nt = 0; nt < 4; ++nt) lp[nt * 16] = f2bf(acc[tt][nt][i]);
      }
    }
  }
}

// Layer-1 aggregation (no matvec): h1 = relu(agg(lin1) + b0) -> bf16
__global__ __launch_bounds__(256) void k_agg(const unsigned short* __restrict__ linbf,
                                             const float* __restrict__ dinv,
                                             const float* __restrict__ bias,
                                             const int* __restrict__ deg,
                                             const int2* __restrict__ ell,
                                             const int* __restrict__ ostart,
                                             const int2* __restrict__ ovf,
                                             unsigned short* __restrict__ hout) {
  int r = blockIdx.x * 4 + (threadIdx.x >> 6);
  if (r >= NN) return;
  int c = threadIdx.x & 63;
  const int4* ellv = (const int4*)(ell + (size_t)r * ELLW);
  int4 q0 = ellv[0], q1 = ellv[1], q2 = ellv[2], q3 = ellv[3];
  int dg = deg[r];
  float dv = dinv[r];
  float bc = bias[c];
  float acc = bf2f(linbf[(size_t)r * 64 + c]) * dv * dv;

  acc = fmaf(asf(q0.y), bf2f(linbf[(size_t)q0.x * 64 + c]), acc);
  acc = fmaf(asf(q0.w), bf2f(linbf[(size_t)q0.z * 64 + c]), acc);
  acc = fmaf(asf(q1.y), bf2f(linbf[(size_t)q1.x * 64 + c]), acc);
  acc = fmaf(asf(q1.w), bf2f(linbf[(size_t)q1.z * 64 + c]), acc);
  if (dg > 4) {
    acc = fmaf(asf(q2.y), bf2f(linbf[(size_t)q2.x * 64 + c]), acc);
    acc = fmaf(asf(q2.w), bf2f(linbf[(size_t)q2.z * 64 + c]), acc);
    acc = fmaf(asf(q3.y), bf2f(linbf[(size_t)q3.x * 64 + c]), acc);
    acc = fmaf(asf(q3.w), bf2f(linbf[(size_t)q3.z * 64 + c]), acc);
  }
  if (dg > ELLW) {
    int rs = ostart[r];
    int on = dg - ELLW;
    for (int j = 0; j < on; j += 4) {
      int2 e0 = ovf[rs + j];
      int2 e1 = ovf[rs + j + 1];
      int2 e2 = ovf[rs + j + 2];
      int2 e3 = ovf[rs + j + 3];
      int rem = on - j;
      float n0 = asf(e0.y);
      float n1 = rem > 1 ? asf(e1.y) : 0.f;
      float n2 = rem > 2 ? asf(e2.y) : 0.f;
      float n3 = rem > 3 ? asf(e3.y) : 0.f;
      int s0 = e0.x;
      int s1 = rem > 1 ? e1.x : r;
      int s2 = rem > 2 ? e2.x : r;
      int s3 = rem > 3 ? e3.x : r;
      acc = fmaf(n0, bf2f(linbf[(size_t)s0 * 64 + c]), acc);
      acc = fmaf(n1, bf2f(linbf[(size_t)s1 * 64 + c]), acc);
      acc = fmaf(n2, bf2f(linbf[(size_t)s2 * 64 + c]), acc);
      acc = fmaf(n3, bf2f(linbf[(size_t)s3 * 64 + c]), acc);
    }
  }
  hout[(size_t)r * 64 + c] = f2bf(fmaxf(acc + bc, 0.f));
}

// Fused layer 2/3: hout = relu( agg(hin) @ W + bias ), using agg(h@W) = agg(h)@W.
// Block = 256 thr = 4 waves = 64 nodes. Phase 1: wave-per-node gather, aggregated row
// -> LDS (bf16). Phase 2 (wave-synchronous, same wave reads its own rows): mini-MFMA
// s[16x64] @ W[64x64] + bias + relu -> hout. No lin buffer, no separate GEMM pass.
__global__ __launch_bounds__(256) void k_layer(const unsigned short* __restrict__ hin,
                                               const float* __restrict__ dinv,
                                               const float* __restrict__ bias,
                                               const int* __restrict__ deg,
                                               const int2* __restrict__ ell,
                                               const int* __restrict__ ostart,
                                               const int2* __restrict__ ovf,
                                               const unsigned short* __restrict__ Wt,  // [n][k] bf16 64x64
                                               unsigned short* __restrict__ hout) {
  constexpr int SP = 72;                    // LDS row stride (bf16): breaks 128B power-of-2 stride
  __shared__ unsigned short Sl[64 * SP];    // 9.2 KB; also stages W (flat 4096) at start
  int tid = threadIdx.x;
  int lane = tid & 63, wave = tid >> 6, quad = lane >> 4, l16 = lane & 15;

  // stage W flat -> B-frags in regs
  for (int idx = tid * 8; idx < 64 * 64; idx += 2048)
    *(short8*)&Sl[idx] = *(const short8*)&Wt[idx];
  __syncthreads();
  short8 bfrag[4][2];
#pragma unroll
  for (int nt = 0; nt < 4; ++nt)
#pragma unroll
    for (int kc = 0; kc < 2; ++kc)
      bfrag[nt][kc] = *(const short8*)&Sl[(nt * 16 + l16) * 64 + kc * 32 + quad * 8];
  float bb[4];
#pragma unroll
  for (int nt = 0; nt < 4; ++nt) bb[nt] = bias[nt * 16 + l16];
  __syncthreads();  // all waves done reading W before phase 1 overwrites Sl

  int base = blockIdx.x * 64 + wave * 16;

  // phase 1: aggregate 16 nodes (wave-wide, lane = feature)
#pragma unroll 4
  for (int j = 0; j < 16; ++j) {
    int r = base + j;
    float acc = 0.f;
    if (r < NN) {
      const int4* ellv = (const int4*)(ell + (size_t)r * ELLW);
      int4 q0 = ellv[0], q1 = ellv[1], q2 = ellv[2], q3 = ellv[3];
      int dg = deg[r];
      float dv = dinv[r];
      acc = bf2f(hin[(size_t)r * 64 + lane]) * dv * dv;
      acc = fmaf(asf(q0.y), bf2f(hin[(size_t)q0.x * 64 + lane]), acc);
      acc = fmaf(asf(q0.w), bf2f(hin[(size_t)q0.z * 64 + lane]), acc);
      acc = fmaf(asf(q1.y), bf2f(hin[(size_t)q1.x * 64 + lane]), acc);
      acc = fmaf(asf(q1.w), bf2f(hin[(size_t)q1.z * 64 + lane]), acc);
      if (dg > 4) {
        acc = fmaf(asf(q2.y), bf2f(hin[(size_t)q2.x * 64 + lane]), acc);
        acc = fmaf(asf(q2.w), bf2f(hin[(size_t)q2.z * 64 + lane]), acc);
        acc = fmaf(asf(q3.y), bf2f(hin[(size_t)q3.x * 64 + lane]), acc);
        acc = fmaf(asf(q3.w), bf2f(hin[(size_t)q3.z * 64 + lane]), acc);
      }
      if (dg > ELLW) {
        int rs = ostart[r];
        int on = dg - ELLW;
        for (int jj = 0; jj < on; jj += 4) {
          int2 e0 = ovf[rs + jj];
          int2 e1 = ovf[rs + jj + 1];
          int2 e2 = ovf[rs + jj + 2];
          int2 e3 = ovf[rs + jj + 3];
          int rem = on - jj;
          float n0 = asf(e0.y);
          float n1 = rem > 1 ? asf(e1.y) : 0.f;
          float n2 = rem > 2 ? asf(e2.y) : 0.f;
          float n3 = rem > 3 ? asf(e3.y) : 0.f;
          int s0 = e0.x;
          int s1 = rem > 1 ? e1.x : r;
          int s2 = rem > 2 ? e2.x : r;
          int s3 = rem > 3 ? e3.x : r;
          acc = fmaf(n0, bf2f(hin[(size_t)s0 * 64 + lane]), acc);
          acc = fmaf(n1, bf2f(hin[(size_t)s1 * 64 + lane]), acc);
          acc = fmaf(n2, bf2f(hin[(size_t)s2 * 64 + lane]), acc);
          acc = fmaf(n3, bf2f(hin[(size_t)s3 * 64 + lane]), acc);
        }
      }
    }
    Sl[(wave * 16 + j) * SP + lane] = f2bf(acc);
  }

  // phase 2: s @ W  (wave reads only its own 16 rows -> no barrier needed)
  floatx4 z = {0.f, 0.f, 0.f, 0.f};
  floatx4 acc[4] = {z, z, z, z};
#pragma unroll
  for (int kc = 0; kc < 2; ++kc) {
    short8 af = *(const short8*)&Sl[(wave * 16 + l16) * SP + kc * 32 + quad * 8];
#pragma unroll
    for (int nt = 0; nt < 4; ++nt)
      acc[nt] = __builtin_amdgcn_mfma_f32_16x16x32_bf16(af, bfrag[nt][kc], acc[nt], 0, 0, 0);
  }
#pragma unroll
  for (int i = 0; i < 4; ++i) {
    int r = base + quad * 4 + i;
    if (r < NN) {
      unsigned short* hp = hout + (size_t)r * 64 + l16;
#pragma unroll
      for (int nt = 0; nt < 4; ++nt)
        hp[nt * 16] = f2bf(fmaxf(acc[nt][i] + bb[nt], 0.f));
    }
  }
}

// one block per graph; 8-way unrolled row stream
__global__ __launch_bounds__(256) void k_pool(const unsigned short* __restrict__ h,
                                              const int* __restrict__ batch,
                                              float* __restrict__ pooled) {
  int g = blockIdx.x;
  int tid = threadIdx.x;
  int c = tid & 63, sub = tid >> 6;

  int lo = 0, hi = NN;
  while (lo < hi) { int mid = (lo + hi) >> 1; if (batch[mid] < g) lo = mid + 1; else hi = mid; }
  int start = lo;
  lo = 0; hi = NN;
  while (lo < hi) { int mid = (lo + hi) >> 1; if (batch[mid] < g + 1) lo = mid + 1; else hi = mid; }
  int end = lo;

  float s = 0.f, m = 0.f;  // relu >= 0 so 0 is a valid max identity; empty graph -> 0 matches ref
  int i = start + sub;
  for (; i + 28 < end; i += 32) {
    float v0 = bf2f(h[(size_t)(i)      * 64 + c]);
    float v1 = bf2f(h[(size_t)(i + 4)  * 64 + c]);
    float v2 = bf2f(h[(size_t)(i + 8)  * 64 + c]);
    float v3 = bf2f(h[(size_t)(i + 12) * 64 + c]);
    float v4 = bf2f(h[(size_t)(i + 16) * 64 + c]);
    float v5 = bf2f(h[(size_t)(i + 20) * 64 + c]);
    float v6 = bf2f(h[(size_t)(i + 24) * 64 + c]);
    float v7 = bf2f(h[(size_t)(i + 28) * 64 + c]);
    s += v0 + v1 + v2 + v3 + v4 + v5 + v6 + v7;
    m = fmaxf(m, fmaxf(fmaxf(fmaxf(v0, v1), fmaxf(v2, v3)),
                       fmaxf(fmaxf(v4, v5), fmaxf(v6, v7))));
  }
  for (; i < end; i += 4) {
    float v = bf2f(h[(size_t)i * 64 + c]);
    s += v;
    m = fmaxf(m, v);
  }
  __shared__ float ss[256], sm[256];
  ss[tid] = s; sm[tid] = m;
  __syncthreads();
  if (sub == 0) {
#pragma unroll
    for (int j = 1; j < 4; ++j) { s += ss[j * 64 + c]; m = fmaxf(m, sm[j * 64 + c]); }
    int cnt = end - start;
    float mean = cnt > 0 ? s / (float)cnt : 0.f;
    pooled[g * 128 + c] = mean;
    pooled[g * 128 + 64 + c] = m;
  }
}

__global__ __launch_bounds__(128) void k_head(const float* __restrict__ pooled,
                                              const float* __restrict__ Wout,
                                              const float* __restrict__ bout,
                                              float* __restrict__ out) {
  __shared__ float p[128];
  int g = blockIdx.x, tid = threadIdx.x;
  p[tid] = pooled[g * 128 + tid];
  __syncthreads();
  if (tid < NC) {
    float acc = bout[tid];
#pragma unroll 8
    for (int c = 0; c < 128; ++c) acc += p[c] * Wout[c * NC + tid];
    out[g * NC + tid] = acc;
  }
}

extern "C" void kernel_launch(void* const* d_in, const int* in_sizes, int n_in,
                              void* d_out, int out_size, void* d_ws, size_t ws_size,
                              hipStream_t stream) {
  const float* x     = (const float*)d_in[0];
  const int*   ei    = (const int*)d_in[1];
  const int*   batch = (const int*)d_in[2];
  const float* W0    = (const float*)d_in[3];
  const float* b0    = (const float*)d_in[4];
  const float* W1    = (const float*)d_in[5];
  const float* b1    = (const float*)d_in[6];
  const float* W2    = (const float*)d_in[7];
  const float* b2    = (const float*)d_in[8];
  const float* Wout  = (const float*)d_in[9];
  const float* bout  = (const float*)d_in[10];
  float* out = (float*)d_out;

  char* ws = (char*)d_ws;
  size_t off = 0;
  auto alloc = [&](size_t bytes) -> void* {
    void* p = ws + off;
    off = (off + bytes + 255) & ~(size_t)255;
    return p;
  };
  int*   deg     = (int*)alloc((size_t)NN * 4);
  int*   odeg    = (int*)alloc((size_t)NN * 4);
  int*   counter = (int*)alloc(4);
  float* dinv    = (float*)alloc((size_t)NN * 4);
  int*   ostart  = (int*)alloc((size_t)NN * 4);
  int*   cur     = (int*)alloc((size_t)NN * 4);
  int2*  ell     = (int2*)alloc((size_t)NN * ELLW * 8);   // 32 MB
  int2*  ovf     = (int2*)alloc(((size_t)NE + 4) * 8);
  unsigned short* linbf = (unsigned short*)alloc((size_t)NN * 64 * 2);
  unsigned short* H1    = (unsigned short*)alloc((size_t)NN * 64 * 2);
  unsigned short* H2    = (unsigned short*)alloc((size_t)NN * 64 * 2);
  unsigned short* Wt0 = (unsigned short*)alloc(64 * 128 * 2);
  unsigned short* Wt1 = (unsigned short*)alloc(64 * 64 * 2);
  unsigned short* Wt2 = (unsigned short*)alloc(64 * 64 * 2);
  float* pooled  = (float*)alloc((size_t)NG * 128 * 4);

  // graph prep
  k_init<<<(NN + 255) / 256, 256, 0, stream>>>(deg, cur, counter);
  k_deg<<<(NE + 255) / 256, 256, 0, stream>>>(ei + NE, deg);
  k_dinv<<<(NN + 255) / 256, 256, 0, stream>>>(deg, dinv, odeg);
  k_rowstart<<<(NN + 255) / 256, 256, 0, stream>>>(odeg, ostart, counter);
  k_ellinit<<<(NN * ELLW + 255) / 256, 256, 0, stream>>>(ell);
  k_fill<<<(NE + 255) / 256, 256, 0, stream>>>(ei, dinv, cur, ell, ostart, ovf);
  k_prepw<<<(128 * 64 + 255) / 256, 256, 0, stream>>>(W0, Wt0, 128);
  k_prepw<<<(64 * 64 + 255) / 256, 256, 0, stream>>>(W1, Wt1, 64);
  k_prepw<<<(64 * 64 + 255) / 256, 256, 0, stream>>>(W2, Wt2, 64);

  // layer 1: transform-first (x is 128-wide; cheaper to shrink before gathering)
  k_gemm_f32<<<2048, 256, 0, stream>>>(x, Wt0, linbf);
  k_agg<<<(NN + 3) / 4, 256, 0, stream>>>(linbf, dinv, b0, deg, ell, ostart, ovf, H1);
  // layers 2,3: aggregate-first fused (agg(h)@W + b, relu) — no lin buffer
  k_layer<<<(NN + 63) / 64, 256, 0, stream>>>(H1, dinv, b1, deg, ell, ostart, ovf, Wt1, H2);
  k_layer<<<(NN + 63) / 64, 256, 0, stream>>>(H2, dinv, b2, deg, ell, ostart, ovf, Wt2, H1);
  // pool + head
  k_pool<<<NG, 256, 0, stream>>>(H1, batch, pooled);
  k_head<<<NG, 128, 0, stream>>>(pooled, Wout, bout, out);
}